// Round 3
// baseline (151.841 us; speedup 1.0000x reference)
//
#include <hip/hip_runtime.h>
#include <hip/hip_bf16.h>

#define N_SEQ 4096
#define DIM   128
#define NH    4
#define DH    32
#define BATCH 4

// scale = (1/sqrt(32)) * log2(e): softmax computed in exp2 domain
#define QSCALE 0.25503495870989204f

typedef __bf16 bf16x8 __attribute__((ext_vector_type(8)));
typedef __bf16 bf16x2 __attribute__((ext_vector_type(2)));
typedef __bf16 bf16x4 __attribute__((ext_vector_type(4)));
typedef float  f32x4  __attribute__((ext_vector_type(4)));

#define MFMA(a, b, c) __builtin_amdgcn_mfma_f32_16x16x32_bf16((a), (b), (c), 0, 0, 0)

static __device__ __forceinline__ bf16x8 cvt8(const float* __restrict__ p) {
    const float4* f4 = reinterpret_cast<const float4*>(p);
    float4 a = f4[0], b = f4[1];
    bf16x8 r;
    r[0] = (__bf16)a.x; r[1] = (__bf16)a.y; r[2] = (__bf16)a.z; r[3] = (__bf16)a.w;
    r[4] = (__bf16)b.x; r[5] = (__bf16)b.y; r[6] = (__bf16)b.z; r[7] = (__bf16)b.w;
    return r;
}

static __device__ __forceinline__ f32x4 exp4(f32x4 s) {
    f32x4 r;
    r[0] = __builtin_amdgcn_exp2f(s[0]);
    r[1] = __builtin_amdgcn_exp2f(s[1]);
    r[2] = __builtin_amdgcn_exp2f(s[2]);
    r[3] = __builtin_amdgcn_exp2f(s[3]);
    return r;
}

// adjacent-pair writes -> compiler can fuse into packed bf16 converts
static __device__ __forceinline__ bf16x8 pack8(f32x4 a, f32x4 b) {
    bf16x8 o;
    o[0] = (__bf16)a[0]; o[1] = (__bf16)a[1];
    o[2] = (__bf16)a[2]; o[3] = (__bf16)a[3];
    o[4] = (__bf16)b[0]; o[5] = (__bf16)b[1];
    o[6] = (__bf16)b[2]; o[7] = (__bf16)b[3];
    return o;
}

// ---------------------------------------------------------------------------
// Kernel 1: fused QKV projection, operand-SWAPPED MFMA (A=W rows, B=x rows).
// (unchanged — held control)
// ---------------------------------------------------------------------------
__global__ __launch_bounds__(256) void proj_qkv(
    const float* __restrict__ xq, const float* __restrict__ xk, const float* __restrict__ xv,
    const float* __restrict__ Wq, const float* __restrict__ Wk, const float* __restrict__ Wv,
    const float* __restrict__ bq, const float* __restrict__ bk, const float* __restrict__ bv,
    __bf16* __restrict__ Qs, __bf16* __restrict__ Kb, __bf16* __restrict__ Vt)
{
    __shared__ __align__(16) char wlds[34816];        // 128 rows x 272 B
    const int z = blockIdx.z;
    const float* x    = (z == 0) ? xq : ((z == 1) ? xk : xv);
    const float* Wf   = (z == 0) ? Wq : ((z == 1) ? Wk : Wv);
    const float* bias = (z == 0) ? bq : ((z == 1) ? bk : bv);
    const int b    = blockIdx.y;
    const int tid  = threadIdx.x;
    const int wave = tid >> 6, lane = tid & 63;
    const int quad = lane >> 4, l15 = lane & 15;
    const int n0   = blockIdx.x * 64 + wave * 16;

    {   // stage W (fp32 -> bf16) into LDS: thread = half-row
        const int r = tid >> 1, half = tid & 1;
        const float* wsrc = Wf + r * DIM + half * 64;
        char* wdst = wlds + r * 272 + half * 128;
        #pragma unroll
        for (int i = 0; i < 8; i++)
            *(bf16x8*)(wdst + i * 16) = cvt8(wsrc + i * 8);
    }

    bf16x8 a[4];
    const float* xrow = x + (b * N_SEQ + n0 + l15) * DIM + quad * 8;
    a[0] = cvt8(xrow);      a[1] = cvt8(xrow + 32);
    a[2] = cvt8(xrow + 64); a[3] = cvt8(xrow + 96);
    __syncthreads();

    const int n = n0 + l15;                    // D col = n (swapped)
    for (int t = 0; t < 8; t++) {
        const char* wr = wlds + (t * 16 + l15) * 272 + quad * 16;
        bf16x8 w0 = *(const bf16x8*)(wr);
        bf16x8 w1 = *(const bf16x8*)(wr + 64);
        bf16x8 w2 = *(const bf16x8*)(wr + 128);
        bf16x8 w3 = *(const bf16x8*)(wr + 192);

        f32x4 acc = {0.f, 0.f, 0.f, 0.f};
        acc = MFMA(w0, a[0], acc);
        acc = MFMA(w1, a[1], acc);
        acc = MFMA(w2, a[2], acc);
        acc = MFMA(w3, a[3], acc);

        const int d0 = t * 16 + quad * 4;      // D row = d0 + r
        if (z == 0) {
            const int h = d0 >> 5, dh0 = d0 & 31;
            bf16x4 q4;
            #pragma unroll
            for (int r = 0; r < 4; r++)
                q4[r] = (__bf16)((acc[r] + bias[d0 + r]) * QSCALE);
            *(bf16x4*)(Qs + ((b * NH + h) * N_SEQ + n) * DH + dh0) = q4;
        } else if (z == 1) {
            const int h = d0 >> 5, dh0 = d0 & 31;
            bf16x4 k4;
            #pragma unroll
            for (int r = 0; r < 4; r++)
                k4[r] = (__bf16)(acc[r] + bias[d0 + r]);
            *(bf16x4*)(Kb + ((b * NH + h) * N_SEQ + n) * DH + dh0) = k4;
        } else {
            const int nl = n & 63;
            const int np = (n & ~63) | (nl & 35) | ((nl & 12) << 1) | ((nl & 16) >> 2);
            #pragma unroll
            for (int r = 0; r < 4; r++) {
                const int d = d0 + r, h = d >> 5, dh = d & 31;
                Vt[((b * NH + h) * DH + dh) * N_SEQ + np] = (__bf16)(acc[r] + bias[d]);
            }
        }
    }
}

// ---------------------------------------------------------------------------
// Kernel 2: attention — LDS-STAGING REMOVED. K/V per head is 512 KB =
// L2-resident (m169 regime: staging cache-fit data is pure overhead).
// Fragments now load directly from global (L2) as 16-B dwordx4, double-
// buffered one 64-key tile ahead (named regs, no runtime indexing).
// This deletes: 16 barriers + vmcnt/lgkm drains, all staging ds_writes,
// all fragment ds_reads, staging addressing VALU, 3.2M bank-conflict
// cycles. The np permutation is baked into Vt at proj time, and LDS was a
// verbatim copy of these tiles — direct global reads are byte-identical.
// Kept from R2 (verified +7%): l-sum via ones-MFMA, setprio clusters,
// 4 waves (2 qh x 2 kh split-K), 64 q/wave. LDS now only the 18.4 KB
// split-K combine buffer; zero barriers in the main loop.
// ---------------------------------------------------------------------------
__global__ __launch_bounds__(256, 2) void flash_attn(
    const __bf16* __restrict__ Qs, const __bf16* __restrict__ Kb,
    const __bf16* __restrict__ Vt, __bf16* __restrict__ ctxb)
{
    __shared__ __align__(16) char smem[18432];   // combine: 128 rows x 144 B

    const int bid  = blockIdx.x;
    const int bh   = bid & 15;                 // consecutive blocks cycle heads
    const int qc   = bid >> 4;                 // 0..31, 128 queries each
    const int tid  = threadIdx.x;
    const int wave = tid >> 6, lane = tid & 63;
    const int quad = lane >> 4, l15 = lane & 15;
    const int qh   = wave & 1, kh = wave >> 1; // kh in {0,1}
    const int n0   = qc * 128 + qh * 64;
    const int KH   = 2048;                     // keys per kh

    // Q B-fragments: 4 tiles of 16 queries
    const __bf16* Qp = Qs + (bh * N_SEQ + n0) * DH;
    bf16x8 qf[4];
    #pragma unroll
    for (int q = 0; q < 4; q++)
        qf[q] = *(const bf16x8*)(Qp + (q * 16 + l15) * DH + quad * 8);

    // ones A-fragment for the l-sum MFMA (l = 1*P summed over frag keys)
    bf16x8 ones;
    #pragma unroll
    for (int i = 0; i < 8; i++) ones[i] = (__bf16)1.0f;

    // per-lane global fragment bases (same cells the LDS copy held)
    const __bf16* gK  = Kb + ((size_t)bh * N_SEQ + kh * KH + l15) * DH + quad * 8;
    const __bf16* gV0 = Vt + ((size_t)bh * DH + l15) * N_SEQ + kh * KH + quad * 8;
    const __bf16* gV1 = gV0 + 16 * N_SEQ;

#define LOADT(t, k0,k1,k2,k3, v0,v1,v2,v3) do {                         \
    const int _t = (t) & 31;                                            \
    const __bf16* _k = gK + (size_t)(_t * 64) * DH;                     \
    k0 = *(const bf16x8*)(_k);                                          \
    k1 = *(const bf16x8*)(_k + 16 * DH);                                \
    k2 = *(const bf16x8*)(_k + 32 * DH);                                \
    k3 = *(const bf16x8*)(_k + 48 * DH);                                \
    v0 = *(const bf16x8*)(gV0 + _t * 64);                               \
    v1 = *(const bf16x8*)(gV1 + _t * 64);                               \
    v2 = *(const bf16x8*)(gV0 + _t * 64 + 32);                          \
    v3 = *(const bf16x8*)(gV1 + _t * 64 + 32);                          \
} while (0)

#define COMPUTE(k0,k1,k2,k3, v0,v1,v2,v3) do {                          \
    bf16x8 pf[4][2];                                                    \
    _Pragma("unroll")                                                   \
    for (int q = 0; q < 4; q++) {                                       \
        __builtin_amdgcn_s_setprio(1);                                  \
        f32x4 sa = MFMA(k0, qf[q], z4);                                 \
        f32x4 sb = MFMA(k1, qf[q], z4);                                 \
        f32x4 sc = MFMA(k2, qf[q], z4);                                 \
        f32x4 sd = MFMA(k3, qf[q], z4);                                 \
        __builtin_amdgcn_s_setprio(0);                                  \
        f32x4 ea = exp4(sa), eb = exp4(sb), ec = exp4(sc), ed = exp4(sd); \
        pf[q][0] = pack8(ea, eb);                                       \
        pf[q][1] = pack8(ec, ed);                                       \
    }                                                                   \
    __builtin_amdgcn_s_setprio(1);                                      \
    _Pragma("unroll")                                                   \
    for (int q = 0; q < 4; q++) {                                       \
        c[q][0] = MFMA(v0, pf[q][0], c[q][0]);                          \
        c[q][1] = MFMA(v1, pf[q][0], c[q][1]);                          \
        c[q][0] = MFMA(v2, pf[q][1], c[q][0]);                          \
        c[q][1] = MFMA(v3, pf[q][1], c[q][1]);                          \
        cl[q]   = MFMA(ones, pf[q][0], cl[q]);                          \
        cl[q]   = MFMA(ones, pf[q][1], cl[q]);                          \
    }                                                                   \
    __builtin_amdgcn_s_setprio(0);                                      \
} while (0)

    f32x4 c[4][2];
    f32x4 cl[4];
    const f32x4 z4 = {0.f,0.f,0.f,0.f};
    #pragma unroll
    for (int q = 0; q < 4; q++) { c[q][0] = z4; c[q][1] = z4; cl[q] = z4; }

    // double-buffered fragment registers (named — rule #20)
    bf16x8 kA0,kA1,kA2,kA3, vA0,vA1,vA2,vA3;
    bf16x8 kB0,kB1,kB2,kB3, vB0,vB1,vB2,vB3;

    LOADT(0, kA0,kA1,kA2,kA3, vA0,vA1,vA2,vA3);

    for (int t = 0; t < 32; t += 2) {          // 32 tiles of 64 keys, no barriers
        LOADT(t + 1, kB0,kB1,kB2,kB3, vB0,vB1,vB2,vB3);
        COMPUTE(kA0,kA1,kA2,kA3, vA0,vA1,vA2,vA3);
        LOADT(t + 2, kA0,kA1,kA2,kA3, vA0,vA1,vA2,vA3);
        COMPUTE(kB0,kB1,kB2,kB3, vB0,vB1,vB2,vB3);
    }

#undef LOADT
#undef COMPUTE

    // split-K combine via LDS
    if (kh == 1) {
        char* dst = smem + (qh * 64 + lane) * 144;
        #pragma unroll
        for (int q = 0; q < 4; q++) {
            *(f32x4*)(dst + (q * 2 + 0) * 16) = c[q][0];
            *(f32x4*)(dst + (q * 2 + 1) * 16) = c[q][1];
        }
        f32x4 lv = {cl[0][0], cl[1][0], cl[2][0], cl[3][0]};
        *(f32x4*)(dst + 128) = lv;
    }
    __syncthreads();
    if (kh == 0) {
        const char* src = smem + (qh * 64 + lane) * 144;
        f32x4 lp = *(const f32x4*)(src + 128);
        const int b = bh >> 2, h = bh & 3;
        #pragma unroll
        for (int q = 0; q < 4; q++) {
            c[q][0] += *(const f32x4*)(src + (q * 2 + 0) * 16);
            c[q][1] += *(const f32x4*)(src + (q * 2 + 1) * 16);
            const float inv = 1.0f / (cl[q][0] + lp[q]);
            const int qg = n0 + q * 16 + l15;
            __bf16* dst = ctxb + ((size_t)(b * N_SEQ + qg)) * DIM + h * DH + quad * 4;
            #pragma unroll
            for (int dt = 0; dt < 2; dt++) {
                f32x4 cc = c[q][dt];
                bf16x2 e0 = {(__bf16)(cc[0] * inv), (__bf16)(cc[1] * inv)};
                bf16x2 e1 = {(__bf16)(cc[2] * inv), (__bf16)(cc[3] * inv)};
                *(bf16x2*)(dst + dt * 16)     = e0;
                *(bf16x2*)(dst + dt * 16 + 2) = e1;
            }
        }
    }
}

// ---------------------------------------------------------------------------
// Kernel 3: output projection, operand-swapped + Wo staged in LDS.
// (unchanged — held control)
// ---------------------------------------------------------------------------
__global__ __launch_bounds__(256) void out_proj(
    const __bf16* __restrict__ ctxb, const float* __restrict__ Wo,
    const float* __restrict__ bo, float* __restrict__ out)
{
    __shared__ __align__(16) char wlds[34816];
    const int b    = blockIdx.y;
    const int tid  = threadIdx.x;
    const int wave = tid >> 6, lane = tid & 63;
    const int quad = lane >> 4, l15 = lane & 15;
    const int n0   = blockIdx.x * 64 + wave * 16;

    {   // stage Wo (fp32 -> bf16) into LDS
        const int r = tid >> 1, half = tid & 1;
        const float* wsrc = Wo + r * DIM + half * 64;
        char* wdst = wlds + r * 272 + half * 128;
        #pragma unroll
        for (int i = 0; i < 8; i++)
            *(bf16x8*)(wdst + i * 16) = cvt8(wsrc + i * 8);
    }

    bf16x8 a[4];
    const __bf16* crow = ctxb + (b * N_SEQ + n0 + l15) * DIM + quad * 8;
    a[0] = *(const bf16x8*)(crow);
    a[1] = *(const bf16x8*)(crow + 32);
    a[2] = *(const bf16x8*)(crow + 64);
    a[3] = *(const bf16x8*)(crow + 96);
    __syncthreads();

    const int n = n0 + l15;
    for (int t = 0; t < 8; t++) {
        const char* wr = wlds + (t * 16 + l15) * 272 + quad * 16;
        bf16x8 w0 = *(const bf16x8*)(wr);
        bf16x8 w1 = *(const bf16x8*)(wr + 64);
        bf16x8 w2 = *(const bf16x8*)(wr + 128);
        bf16x8 w3 = *(const bf16x8*)(wr + 192);

        f32x4 acc = {0.f, 0.f, 0.f, 0.f};
        acc = MFMA(w0, a[0], acc);
        acc = MFMA(w1, a[1], acc);
        acc = MFMA(w2, a[2], acc);
        acc = MFMA(w3, a[3], acc);

        const int d0 = t * 16 + quad * 4;
        float4 o;
        o.x = acc[0] + bo[d0];
        o.y = acc[1] + bo[d0 + 1];
        o.z = acc[2] + bo[d0 + 2];
        o.w = acc[3] + bo[d0 + 3];
        *(float4*)(out + (b * N_SEQ + n) * DIM + d0) = o;
    }
}

// ---------------------------------------------------------------------------
extern "C" void kernel_launch(void* const* d_in, const int* in_sizes, int n_in,
                              void* d_out, int out_size, void* d_ws, size_t ws_size,
                              hipStream_t stream)
{
    const float* query = (const float*)d_in[0];
    const float* key   = (const float*)d_in[1];
    const float* value = (const float*)d_in[2];
    const float* Wq = (const float*)d_in[3];
    const float* bq = (const float*)d_in[4];
    const float* Wk = (const float*)d_in[5];
    const float* bk = (const float*)d_in[6];
    const float* Wv = (const float*)d_in[7];
    const float* bv = (const float*)d_in[8];
    const float* Wo = (const float*)d_in[9];
    const float* bo = (const float*)d_in[10];
    float* out = (float*)d_out;

    char* ws = (char*)d_ws;
    const size_t e = (size_t)BATCH * N_SEQ * DIM;   // 2,097,152 elements
    __bf16* Qs   = (__bf16*)(ws);                   // 4 MB  [B,H,N,32] scaled
    __bf16* Kb   = (__bf16*)(ws + 2 * e);           // 4 MB  [B,H,N,32] identity
    __bf16* Vt   = (__bf16*)(ws + 4 * e);           // 4 MB  [B,H,32,N] key-permuted
    __bf16* ctxb = (__bf16*)(ws + 6 * e);           // 4 MB  [B,N,128]

    proj_qkv<<<dim3(64, BATCH, 3), 256, 0, stream>>>(
        query, key, value, Wq, Wk, Wv, bq, bk, bv, Qs, Kb, Vt);
    flash_attn<<<dim3(512), 256, 0, stream>>>(Qs, Kb, Vt, ctxb);
    out_proj<<<dim3(64, BATCH), 256, 0, stream>>>(ctxb, Wo, bo, out);
}